// Round 8
// baseline (6259.547 us; speedup 1.0000x reference)
//
#include <hip/hip_runtime.h>
#include <hip/hip_bf16.h>
#include <math.h>

#define N_NODES 50000
#define N_EDGES 800000
#define GK 256
#define TS 288   // padded table row stride in US (576B): slice lines 9j+s -> full L2 set coverage
#define NGROUPS 12500   // node-groups (4 nodes each) per slice
#define G256_TILES_PER_XCD 98
#define G64_TILES_PER_XCD 49

typedef unsigned short US;
typedef unsigned long long ULL;
typedef __attribute__((ext_vector_type(8))) short short8;
typedef __attribute__((ext_vector_type(4))) float floatx4;
typedef __attribute__((address_space(1))) const void* gptr_t;
typedef __attribute__((address_space(3))) void* lptr_t;

static __device__ __forceinline__ float bflo(unsigned int u) {
  union { unsigned int i; float f; } c; c.i = u << 16; return c.f;
}
static __device__ __forceinline__ float bfhi(unsigned int u) {
  union { unsigned int i; float f; } c; c.i = u & 0xffff0000u; return c.f;
}
static __device__ __forceinline__ float bf2f(US u) {
  union { unsigned int i; float f; } c; c.i = ((unsigned int)u) << 16; return c.f;
}
static __device__ __forceinline__ US f2bf(float f) {  // round-to-nearest-even
  union { float f; unsigned int i; } c; c.f = f;
  unsigned int x = c.i;
  return (US)((x + 0x7fffu + ((x >> 16) & 1u)) >> 16);
}

// ----------------- preprocessing -----------------

__global__ void pre0_kernel(const int* __restrict__ col, int* __restrict__ cnt,
                            const float* __restrict__ x, US* __restrict__ xb,
                            const float* __restrict__ W1, const float* __restrict__ W2,
                            const float* __restrict__ W3,
                            US* __restrict__ Wt1, US* __restrict__ Wt2,
                            US* __restrict__ Wt3, int* __restrict__ ctrs) {
  int gt = blockIdx.x * 256 + threadIdx.x;
  int gs = gridDim.x * 256;
  if (gt < 64) ctrs[gt] = 0;                      // per-layer slice work counters
  for (int e = gt; e < N_EDGES; e += gs) atomicAdd(&cnt[col[e]], 1);
  for (int i = gt; i < N_NODES * 64; i += gs) {   // x: 12.8M elems / 4
    float4 v = *(const float4*)(x + (size_t)i * 4);
    US o[4] = { f2bf(v.x), f2bf(v.y), f2bf(v.z), f2bf(v.w) };
    int row = i >> 6, c4 = (i & 63) << 2;
    *(ushort4*)(xb + (size_t)row * TS + c4) = *(ushort4*)o;
  }
  for (int idx = gt; idx < 147456; idx += gs) {
    if (idx < 65536) {
      int k = idx >> 8, n = idx & 255;
      Wt1[n * 256 + k] = f2bf(W1[idx]);
    } else if (idx < 131072) {
      int i = idx - 65536, k = i >> 8, n = i & 255;
      Wt2[n * 256 + k] = f2bf(W2[i]);
    } else {
      int i = idx - 131072, k = i >> 6, n = i & 63;
      Wt3[n * 256 + k] = f2bf(W3[i]);
    }
  }
}

__global__ void scan_block_kernel(const int* __restrict__ in, int* __restrict__ out,
                                  int* __restrict__ bsums, float* __restrict__ dinv, int n) {
  __shared__ int s[256];
  int gid = blockIdx.x * 256 + threadIdx.x;
  int v = (gid < n) ? in[gid] : 0;
  if (gid < n) dinv[gid] = 1.0f / sqrtf((float)(v + 1));  // +1 self-loop
  s[threadIdx.x] = v;
  __syncthreads();
  for (int off = 1; off < 256; off <<= 1) {
    int t = (threadIdx.x >= off) ? s[threadIdx.x - off] : 0;
    __syncthreads();
    s[threadIdx.x] += t;
    __syncthreads();
  }
  if (gid < n) out[gid] = s[threadIdx.x] - v;  // exclusive
  if (threadIdx.x == 255) bsums[blockIdx.x] = s[255];
}

__global__ void scan_top_kernel(int* __restrict__ bsums, int n) {
  __shared__ int s[256];
  int v = (threadIdx.x < n) ? bsums[threadIdx.x] : 0;
  s[threadIdx.x] = v;
  __syncthreads();
  for (int off = 1; off < 256; off <<= 1) {
    int t = (threadIdx.x >= off) ? s[threadIdx.x - off] : 0;
    __syncthreads();
    s[threadIdx.x] += t;
    __syncthreads();
  }
  if (threadIdx.x < n) bsums[threadIdx.x] = s[threadIdx.x] - v;
}

__global__ void scan_add_kernel(int* __restrict__ row_ptr, int* __restrict__ fill,
                                const int* __restrict__ bsums, int n) {
  int gid = blockIdx.x * 256 + threadIdx.x;
  if (gid < n) {
    int v = row_ptr[gid] + bsums[blockIdx.x];
    row_ptr[gid] = v;
    fill[gid] = v;
  }
}

__global__ void fill_kernel(const int* __restrict__ row, const int* __restrict__ col,
                            int* __restrict__ fill, int2* __restrict__ srcs2,
                            const float* __restrict__ dinv, int E) {
  int e = blockIdx.x * blockDim.x + threadIdx.x;
  if (e < E) {
    int d = col[e];
    int r = row[e];
    int pos = atomicAdd(&fill[d], 1);
    srcs2[pos] = make_int2(r, __float_as_int(dinv[r]));
  }
}

// ----------------- gemm256: C[M,256](stride TS) = A[M,256](stride TS) @ Wt^T -----------------

__global__ __launch_bounds__(256) void gemm256_kernel(
    const US* __restrict__ A, const US* __restrict__ Wt,
    US* __restrict__ C, int M) {
  __shared__ __align__(16) US shm[24576];      // 48KB
  int tid = threadIdx.x;
  int L = blockIdx.x;
  int xcd = L & 7, kk = L >> 3;
  int bmIdx = xcd * G256_TILES_PER_XCD + (kk >> 1);
  int bm = bmIdx * 64;
  int bn = (kk & 1) * 128;
  int lane = tid & 63;
  int w = tid >> 6;
  int wc = w * 32;
  int lm = lane & 15, lk = lane >> 4;
  int lr = lane >> 3, lc = lane & 7;
  int gc = lc ^ lr;

  floatx4 zero = {0.f, 0.f, 0.f, 0.f};
  floatx4 acc[4][2];
#pragma unroll
  for (int i = 0; i < 4; ++i)
#pragma unroll
    for (int j = 0; j < 2; ++j) acc[i][j] = zero;

  auto issue = [&](int k, int b) {
    int k0 = k * 64;
    US* As = shm + b * 4096;
    US* Bs = shm + 8192 + b * 8192;
#pragma unroll
    for (int i = 0; i < 2; ++i) {
      int rbase = i * 32 + w * 8;
      int r = min(bm + rbase + lr, M - 1);
      const US* ga = A + (size_t)r * TS + k0 + gc * 8;
      __builtin_amdgcn_global_load_lds((gptr_t)(const void*)ga,
                                       (lptr_t)(void*)&As[rbase * 64], 16, 0, 0);
    }
#pragma unroll
    for (int i = 0; i < 4; ++i) {
      int rbase = i * 32 + w * 8;
      int r = bn + rbase + lr;
      const US* gb = Wt + (size_t)r * GK + k0 + gc * 8;
      __builtin_amdgcn_global_load_lds((gptr_t)(const void*)gb,
                                       (lptr_t)(void*)&Bs[rbase * 64], 16, 0, 0);
    }
  };

  issue(0, 0);
#pragma unroll
  for (int k = 0; k < 4; ++k) {
    if (k < 3) {
      issue(k + 1, (k + 1) & 1);
      asm volatile("s_waitcnt vmcnt(6)" ::: "memory");
    } else {
      asm volatile("s_waitcnt vmcnt(0)" ::: "memory");
    }
    __builtin_amdgcn_sched_barrier(0);
    __builtin_amdgcn_s_barrier();
    const US* As = shm + (k & 1) * 4096;
    const US* Bs = shm + 8192 + (k & 1) * 8192;
#pragma unroll
    for (int s = 0; s < 2; ++s) {
      short8 af[4], bfr[2];
#pragma unroll
      for (int i = 0; i < 4; ++i) {
        int row = i * 16 + lm;
        int c = (s * 4 + lk) ^ (row & 7);
        af[i] = *(const short8*)&As[row * 64 + c * 8];
      }
#pragma unroll
      for (int j = 0; j < 2; ++j) {
        int row = wc + j * 16 + lm;
        int c = (s * 4 + lk) ^ (row & 7);
        bfr[j] = *(const short8*)&Bs[row * 64 + c * 8];
      }
#pragma unroll
      for (int i = 0; i < 4; ++i)
#pragma unroll
        for (int j = 0; j < 2; ++j)
          acc[i][j] = __builtin_amdgcn_mfma_f32_16x16x32_bf16(af[i], bfr[j], acc[i][j], 0, 0, 0);
    }
    __builtin_amdgcn_s_barrier();
  }

  {
    constexpr int LDC = 136;
    US* Cs = shm;
#pragma unroll
    for (int i = 0; i < 4; ++i)
#pragma unroll
      for (int j = 0; j < 2; ++j) {
        int colg = wc + j * 16 + lm;
#pragma unroll
        for (int r = 0; r < 4; ++r)
          Cs[(i * 16 + lk * 4 + r) * LDC + colg] = f2bf(acc[i][j][r]);
      }
    __syncthreads();
#pragma unroll
    for (int c = 0; c < 4; ++c) {
      int idx = tid + c * 256;
      int row = idx >> 4;
      int ch = idx & 15;
      uint4 v = *(const uint4*)&Cs[row * LDC + ch * 8];
      if (bm + row < M) *(uint4*)&C[(size_t)(bm + row) * TS + bn + ch * 8] = v;
    }
  }
}

// ----------------- gemm64: C[M,64] = A[M,256](stride TS) @ Wt3^T -----------------

__global__ __launch_bounds__(256) void gemm64_kernel(
    const US* __restrict__ A, const US* __restrict__ Wt,
    US* __restrict__ C, int M) {
  __shared__ __align__(16) US shm[24576];
  int tid = threadIdx.x;
  int L = blockIdx.x;
  int b = (L & 7) * G64_TILES_PER_XCD + (L >> 3);
  int bm = b * 128;
  int lane = tid & 63;
  int w = tid >> 6;
  int wr = w * 32;
  int lm = lane & 15, lk = lane >> 4;
  int lr = lane >> 3, lc = lane & 7;
  int gc = lc ^ lr;

  floatx4 zero = {0.f, 0.f, 0.f, 0.f};
  floatx4 acc[2][4];
#pragma unroll
  for (int i = 0; i < 2; ++i)
#pragma unroll
    for (int j = 0; j < 4; ++j) acc[i][j] = zero;

  auto issue = [&](int k, int bb) {
    int k0 = k * 64;
    US* As = shm + bb * 8192;
    US* Bs = shm + 16384 + bb * 4096;
#pragma unroll
    for (int i = 0; i < 4; ++i) {
      int rbase = i * 32 + w * 8;
      int r = min(bm + rbase + lr, M - 1);
      const US* ga = A + (size_t)r * TS + k0 + gc * 8;
      __builtin_amdgcn_global_load_lds((gptr_t)(const void*)ga,
                                       (lptr_t)(void*)&As[rbase * 64], 16, 0, 0);
    }
#pragma unroll
    for (int i = 0; i < 2; ++i) {
      int rbase = i * 32 + w * 8;
      int r = rbase + lr;
      const US* gb = Wt + (size_t)r * GK + k0 + gc * 8;
      __builtin_amdgcn_global_load_lds((gptr_t)(const void*)gb,
                                       (lptr_t)(void*)&Bs[rbase * 64], 16, 0, 0);
    }
  };

  issue(0, 0);
#pragma unroll
  for (int k = 0; k < 4; ++k) {
    if (k < 3) {
      issue(k + 1, (k + 1) & 1);
      asm volatile("s_waitcnt vmcnt(6)" ::: "memory");
    } else {
      asm volatile("s_waitcnt vmcnt(0)" ::: "memory");
    }
    __builtin_amdgcn_sched_barrier(0);
    __builtin_amdgcn_s_barrier();
    const US* As = shm + (k & 1) * 8192;
    const US* Bs = shm + 16384 + (k & 1) * 4096;
#pragma unroll
    for (int s = 0; s < 2; ++s) {
      short8 af[2], bfr[4];
#pragma unroll
      for (int i = 0; i < 2; ++i) {
        int row = wr + i * 16 + lm;
        int c = (s * 4 + lk) ^ (row & 7);
        af[i] = *(const short8*)&As[row * 64 + c * 8];
      }
#pragma unroll
      for (int j = 0; j < 4; ++j) {
        int row = j * 16 + lm;
        int c = (s * 4 + lk) ^ (row & 7);
        bfr[j] = *(const short8*)&Bs[row * 64 + c * 8];
      }
#pragma unroll
      for (int i = 0; i < 2; ++i)
#pragma unroll
        for (int j = 0; j < 4; ++j)
          acc[i][j] = __builtin_amdgcn_mfma_f32_16x16x32_bf16(af[i], bfr[j], acc[i][j], 0, 0, 0);
    }
    __builtin_amdgcn_s_barrier();
  }

  {
    constexpr int LDC = 72;
    US* Cs = shm;
#pragma unroll
    for (int i = 0; i < 2; ++i)
#pragma unroll
      for (int j = 0; j < 4; ++j) {
        int colg = j * 16 + lm;
#pragma unroll
        for (int r = 0; r < 4; ++r)
          Cs[(wr + i * 16 + lk * 4 + r) * LDC + colg] = f2bf(acc[i][j][r]);
      }
    __syncthreads();
#pragma unroll
    for (int c = 0; c < 4; ++c) {
      int idx = tid + c * 256;
      int row = idx >> 3;
      int ch = idx & 7;
      uint4 v = *(const uint4*)&Cs[row * LDC + ch * 8];
      if (bm + row < M) *(uint4*)&C[(size_t)(bm + row) * 64 + ch * 8] = v;
    }
  }
}

// ----------------- dim-sliced aggregation v3 (R8): HW-pinned persistent workers ---
// R6/R7 failed because blockIdx->XCD round-robin DRIFTS for variable-duration
// blocks (hit rate identical to unsliced). v3 pins by hardware: each block reads
// its physical chiplet id via s_getreg(HW_REG_XCC_ID) [m09] and pulls work for
// slice s = xcc from a per-slice atomic queue -> every slice-s gather provably
// runs on XCD s; hot set = 3.2MB slice < 4MB L2 (set-spread via TS=288).
// srcs2 + output nontemporal so they don't evict the slice.

template <bool RELU>
__global__ __launch_bounds__(256) void aggslice_kernel(
    const US* __restrict__ t, US* __restrict__ out,
    const int* __restrict__ row_ptr, const int* __restrict__ cnt,
    const int2* __restrict__ srcs2, const float* __restrict__ dinv,
    const float* __restrict__ bias, int* __restrict__ ctr) {
  __shared__ int sh_g;
  int xcc;
  asm volatile("s_getreg_b32 %0, hwreg(HW_REG_XCC_ID)" : "=s"(xcc));
  int s = xcc & 7;                // physical XCD == dim-slice
  int tid = threadIdx.x;
  int wv = tid >> 6;
  int lane = tid & 63;
  int es = lane >> 2;             // edge-sub 0..15
  int qd = lane & 3;              // 16B quarter of the 64B slice
  int dbase = s * 32 + qd * 8;    // US offset within row
  const ULL* srcsu = (const ULL*)srcs2;

  for (;;) {
    if (tid == 0) sh_g = atomicAdd(&ctr[s], 1);
    __syncthreads();
    int g = sh_g;
    if (g >= NGROUPS) return;     // uniform exit
    int j = g * 4 + wv;

    int start = row_ptr[j];
    int n = cnt[j];
    float a0 = 0.f, a1 = 0.f, a2 = 0.f, a3 = 0.f;
    float a4 = 0.f, a5 = 0.f, a6 = 0.f, a7 = 0.f;
    for (int i = 0; i < n; i += 16) {
      int idx = i + es;
      int cl = min(idx, n - 1);
      ULL e = __builtin_nontemporal_load(&srcsu[start + cl]);
      int src = (int)(unsigned int)e;
      float w = (idx < n) ? __int_as_float((unsigned int)(e >> 32)) : 0.f;
      uint4 v = *(const uint4*)(t + (size_t)src * TS + dbase);
      a0 += bflo(v.x) * w; a1 += bfhi(v.x) * w;
      a2 += bflo(v.y) * w; a3 += bfhi(v.y) * w;
      a4 += bflo(v.z) * w; a5 += bfhi(v.z) * w;
      a6 += bflo(v.w) * w; a7 += bfhi(v.w) * w;
    }
#pragma unroll
    for (int st = 4; st <= 32; st <<= 1) {
      a0 += __shfl_xor(a0, st, 64); a1 += __shfl_xor(a1, st, 64);
      a2 += __shfl_xor(a2, st, 64); a3 += __shfl_xor(a3, st, 64);
      a4 += __shfl_xor(a4, st, 64); a5 += __shfl_xor(a5, st, 64);
      a6 += __shfl_xor(a6, st, 64); a7 += __shfl_xor(a7, st, 64);
    }

    float dj = dinv[j];
    uint4 vj = *(const uint4*)(t + (size_t)j * TS + dbase);
    float4 bv0 = *(const float4*)(bias + dbase);
    float4 bv1 = *(const float4*)(bias + dbase + 4);
    float r0 = (a0 + bflo(vj.x) * dj) * dj + bv0.x;
    float r1 = (a1 + bfhi(vj.x) * dj) * dj + bv0.y;
    float r2 = (a2 + bflo(vj.y) * dj) * dj + bv0.z;
    float r3 = (a3 + bfhi(vj.y) * dj) * dj + bv0.w;
    float r4 = (a4 + bflo(vj.z) * dj) * dj + bv1.x;
    float r5 = (a5 + bfhi(vj.z) * dj) * dj + bv1.y;
    float r6 = (a6 + bflo(vj.w) * dj) * dj + bv1.z;
    float r7 = (a7 + bfhi(vj.w) * dj) * dj + bv1.w;
    if (RELU) {
      r0 = fmaxf(r0, 0.f); r1 = fmaxf(r1, 0.f);
      r2 = fmaxf(r2, 0.f); r3 = fmaxf(r3, 0.f);
      r4 = fmaxf(r4, 0.f); r5 = fmaxf(r5, 0.f);
      r6 = fmaxf(r6, 0.f); r7 = fmaxf(r7, 0.f);
    }
    if (lane < 4) {               // es==0 lanes: 4 lanes x 16B = 64B store
      ULL lo = ((ULL)(((unsigned int)f2bf(r3) << 16) | f2bf(r2)) << 32)
             | (ULL)(((unsigned int)f2bf(r1) << 16) | f2bf(r0));
      ULL hi = ((ULL)(((unsigned int)f2bf(r7) << 16) | f2bf(r6)) << 32)
             | (ULL)(((unsigned int)f2bf(r5) << 16) | f2bf(r4));
      ULL* op = (ULL*)(out + (size_t)j * TS + dbase);
      __builtin_nontemporal_store(lo, op);
      __builtin_nontemporal_store(hi, op + 1);
    }
    __syncthreads();              // all threads done with sh_g before next grab
  }
}

// ----------------- fused agg64 + final dense + sigmoid (R3, kept) -----------------

__global__ __launch_bounds__(256) void aggfinal_kernel(
    const US* __restrict__ t, float* __restrict__ out,
    const int* __restrict__ row_ptr, const int* __restrict__ cnt,
    const int2* __restrict__ srcs2, const float* __restrict__ dinv,
    const float* __restrict__ b3, const float* __restrict__ W4,
    const float* __restrict__ b4, int M) {
  __shared__ float W4s[4096];
  __shared__ float b4s[64];
  __shared__ float hbuf[4][64];
  int tid = threadIdx.x;
#pragma unroll
  for (int it = 0; it < 16; ++it) W4s[it * 256 + tid] = W4[it * 256 + tid];
  if (tid < 64) b4s[tid] = b4[tid];
  __syncthreads();

  int wv = tid >> 6, lane = tid & 63;
  int g = lane & 15, eidx = lane >> 4;
  int base = g * 4;
#pragma unroll 1
  for (int q = 0; q < 4; ++q) {
    int j = blockIdx.x * 16 + wv * 4 + q;
    if (j >= M) break;
    int start = row_ptr[j];
    int n = cnt[j];
    float a[4] = {0.f, 0.f, 0.f, 0.f};
    int i = 0;
    for (; i + 7 < n; i += 8) {
      int2 e0 = srcs2[start + i + eidx];
      int2 e1 = srcs2[start + i + 4 + eidx];
      uint2 v0 = *(const uint2*)(t + (size_t)e0.x * 64 + base);
      uint2 v1 = *(const uint2*)(t + (size_t)e1.x * 64 + base);
      float w0 = __int_as_float(e0.y), w1 = __int_as_float(e1.y);
      a[0] += bflo(v0.x) * w0; a[1] += bfhi(v0.x) * w0;
      a[2] += bflo(v0.y) * w0; a[3] += bfhi(v0.y) * w0;
      a[0] += bflo(v1.x) * w1; a[1] += bfhi(v1.x) * w1;
      a[2] += bflo(v1.y) * w1; a[3] += bfhi(v1.y) * w1;
    }
    for (; i < n; i += 4) {
      int idx = i + eidx;
      int cl = min(idx, n - 1);
      int2 e = srcs2[start + cl];
      float w0 = (idx < n) ? __int_as_float(e.y) : 0.f;
      uint2 v = *(const uint2*)(t + (size_t)e.x * 64 + base);
      a[0] += bflo(v.x) * w0; a[1] += bfhi(v.x) * w0;
      a[2] += bflo(v.y) * w0; a[3] += bfhi(v.y) * w0;
    }
#pragma unroll
    for (int k = 0; k < 4; ++k) {
      a[k] += __shfl_xor(a[k], 16, 64);
      a[k] += __shfl_xor(a[k], 32, 64);
    }
    float dj = dinv[j];
    uint2 vj = *(const uint2*)(t + (size_t)j * 64 + base);
    float4 bv = *(const float4*)(b3 + base);
    float h0 = (a[0] + bflo(vj.x) * dj) * dj + bv.x;
    float h1 = (a[1] + bfhi(vj.x) * dj) * dj + bv.y;
    float h2 = (a[2] + bflo(vj.y) * dj) * dj + bv.z;
    float h3 = (a[3] + bfhi(vj.y) * dj) * dj + bv.w;
    if (lane < 16) {
      float4 hv = make_float4(h0, h1, h2, h3);
      *(float4*)&hbuf[wv][base] = hv;
    }
    asm volatile("s_waitcnt lgkmcnt(0)" ::: "memory");
    float acc = b4s[lane];
#pragma unroll 8
    for (int k = 0; k < 64; ++k) acc += hbuf[wv][k] * W4s[k * 64 + lane];
    out[(size_t)j * 64 + lane] = 1.0f / (1.0f + expf(-acc));
  }
}

// ----------------- driver -----------------

extern "C" void kernel_launch(void* const* d_in, const int* in_sizes, int n_in,
                              void* d_out, int out_size, void* d_ws, size_t ws_size,
                              hipStream_t stream) {
  const float* x  = (const float*)d_in[0];
  const int* ei   = (const int*)d_in[1];
  const float* W1 = (const float*)d_in[2];
  const float* b1 = (const float*)d_in[3];
  const float* W2 = (const float*)d_in[4];
  const float* b2 = (const float*)d_in[5];
  const float* W3 = (const float*)d_in[6];
  const float* b3 = (const float*)d_in[7];
  const float* W4 = (const float*)d_in[8];
  const float* b4 = (const float*)d_in[9];
  float* outp = (float*)d_out;

  const int N = N_NODES, E = N_EDGES;
  const int* row = ei;
  const int* col = ei + E;

  US* Ab = (US*)d_ws;                         // [N,TS] bf16 ping (padded stride)
  US* Bb = Ab + (size_t)N * TS;               // [N,TS] bf16 pong
  US* B64 = Bb + (size_t)N * TS;              // [N,64] (G6)
  float* dinv = (float*)(B64 + (size_t)N * 64);
  int* cnt = (int*)(dinv + N);
  int* row_ptr = cnt + N;
  int* fill = row_ptr + N;
  int* bsums = fill + N;                      // [256]
  int* ctrs = bsums + 256;                    // [64]: 5 layers x 8 slice counters
  int2* srcs2 = (int2*)(ctrs + 64);           // [E]
  US* Wt1 = (US*)(srcs2 + E);                 // [256,256]
  US* Wt2 = Wt1 + 256 * 256;                  // [256,256]
  US* Wt3 = Wt2 + 256 * 256;                  // [64,256]

  hipMemsetAsync(cnt, 0, N * sizeof(int), stream);
  pre0_kernel<<<1024, 256, 0, stream>>>(col, cnt, x, Ab, W1, W2, W3,
                                        Wt1, Wt2, Wt3, ctrs);
  int nblk = (N + 255) / 256;
  scan_block_kernel<<<nblk, 256, 0, stream>>>(cnt, row_ptr, bsums, dinv, N);
  scan_top_kernel<<<1, 256, 0, stream>>>(bsums, nblk);
  scan_add_kernel<<<nblk, 256, 0, stream>>>(row_ptr, fill, bsums, N);
  fill_kernel<<<(E + 255) / 256, 256, 0, stream>>>(row, col, fill, srcs2, dinv, E);

  const int g256 = 8 * G256_TILES_PER_XCD * 2;   // 1568
  const int g64g = 8 * G64_TILES_PER_XCD;        // 392
  const int gagg = 4096;                         // persistent workers

  gemm256_kernel<<<g256, 256, 0, stream>>>(Ab, Wt1, Bb, N);
  aggslice_kernel<true><<<gagg, 256, 0, stream>>>(Bb, Ab, row_ptr, cnt, srcs2, dinv, b1, ctrs + 0);
  for (int l = 0; l < 4; ++l) {
    gemm256_kernel<<<g256, 256, 0, stream>>>(Ab, Wt2, Bb, N);
    aggslice_kernel<true><<<gagg, 256, 0, stream>>>(Bb, Ab, row_ptr, cnt, srcs2, dinv, b2,
                                                    ctrs + 8 * (l + 1));
  }
  gemm64_kernel<<<g64g, 256, 0, stream>>>(Ab, Wt3, B64, N);
  aggfinal_kernel<<<(N + 15) / 16, 256, 0, stream>>>(B64, outp, row_ptr, cnt, srcs2, dinv,
                                                     b3, W4, b4, N);
}

// Round 9
// 599.289 us; speedup vs baseline: 10.4449x; 10.4449x over previous
//
#include <hip/hip_runtime.h>
#include <hip/hip_bf16.h>
#include <math.h>

#define N_NODES 50000
#define N_EDGES 800000
#define GK 256
// XCD chunking: 6272 nodes/chunk (= 98 gemm256-tiles x 64 = 49 gemm64-tiles x 128
// = 1568 agg-blocks x 4). 8 chunks cover 50176 >= N.
#define AGG_BLKS_PER_XCD 1568
#define G256_TILES_PER_XCD 98
#define G64_TILES_PER_XCD 49

typedef unsigned short US;
typedef __attribute__((ext_vector_type(8))) short short8;
typedef __attribute__((ext_vector_type(4))) float floatx4;
typedef __attribute__((address_space(1))) const void* gptr_t;
typedef __attribute__((address_space(3))) void* lptr_t;

static __device__ __forceinline__ float bflo(unsigned int u) {
  union { unsigned int i; float f; } c; c.i = u << 16; return c.f;
}
static __device__ __forceinline__ float bfhi(unsigned int u) {
  union { unsigned int i; float f; } c; c.i = u & 0xffff0000u; return c.f;
}
static __device__ __forceinline__ float bf2f(US u) {
  union { unsigned int i; float f; } c; c.i = ((unsigned int)u) << 16; return c.f;
}
static __device__ __forceinline__ US f2bf(float f) {  // round-to-nearest-even
  union { float f; unsigned int i; } c; c.f = f;
  unsigned int x = c.i;
  return (US)((x + 0x7fffu + ((x >> 16) & 1u)) >> 16);
}

// ----------------- preprocessing -----------------

__global__ void pre0_kernel(const int* __restrict__ col, int* __restrict__ cnt,
                            const float* __restrict__ x, US* __restrict__ xb,
                            const float* __restrict__ W1, const float* __restrict__ W2,
                            const float* __restrict__ W3,
                            US* __restrict__ Wt1, US* __restrict__ Wt2,
                            US* __restrict__ Wt3) {
  int gt = blockIdx.x * 256 + threadIdx.x;
  int gs = gridDim.x * 256;
  for (int e = gt; e < N_EDGES; e += gs) atomicAdd(&cnt[col[e]], 1);
  for (int i = gt; i < N_NODES * 64; i += gs) {   // x: 12.8M elems / 4
    float4 v = *(const float4*)(x + (size_t)i * 4);
    US o[4] = { f2bf(v.x), f2bf(v.y), f2bf(v.z), f2bf(v.w) };
    *(ushort4*)(xb + (size_t)i * 4) = *(ushort4*)o;
  }
  for (int idx = gt; idx < 147456; idx += gs) {
    if (idx < 65536) {
      int k = idx >> 8, n = idx & 255;
      Wt1[n * 256 + k] = f2bf(W1[idx]);
    } else if (idx < 131072) {
      int i = idx - 65536, k = i >> 8, n = i & 255;
      Wt2[n * 256 + k] = f2bf(W2[i]);
    } else {
      int i = idx - 131072, k = i >> 6, n = i & 63;
      Wt3[n * 256 + k] = f2bf(W3[i]);
    }
  }
}

__global__ void scan_block_kernel(const int* __restrict__ in, int* __restrict__ out,
                                  int* __restrict__ bsums, float* __restrict__ dinv, int n) {
  __shared__ int s[256];
  int gid = blockIdx.x * 256 + threadIdx.x;
  int v = (gid < n) ? in[gid] : 0;
  if (gid < n) dinv[gid] = 1.0f / sqrtf((float)(v + 1));  // +1 self-loop
  s[threadIdx.x] = v;
  __syncthreads();
  for (int off = 1; off < 256; off <<= 1) {
    int t = (threadIdx.x >= off) ? s[threadIdx.x - off] : 0;
    __syncthreads();
    s[threadIdx.x] += t;
    __syncthreads();
  }
  if (gid < n) out[gid] = s[threadIdx.x] - v;  // exclusive
  if (threadIdx.x == 255) bsums[blockIdx.x] = s[255];
}

__global__ void scan_top_kernel(int* __restrict__ bsums, int n) {
  __shared__ int s[256];
  int v = (threadIdx.x < n) ? bsums[threadIdx.x] : 0;
  s[threadIdx.x] = v;
  __syncthreads();
  for (int off = 1; off < 256; off <<= 1) {
    int t = (threadIdx.x >= off) ? s[threadIdx.x - off] : 0;
    __syncthreads();
    s[threadIdx.x] += t;
    __syncthreads();
  }
  if (threadIdx.x < n) bsums[threadIdx.x] = s[threadIdx.x] - v;
}

__global__ void scan_add_kernel(int* __restrict__ row_ptr, int* __restrict__ fill,
                                const int* __restrict__ bsums, int n) {
  int gid = blockIdx.x * 256 + threadIdx.x;
  if (gid < n) {
    int v = row_ptr[gid] + bsums[blockIdx.x];
    row_ptr[gid] = v;
    fill[gid] = v;
  }
}

__global__ void fill_kernel(const int* __restrict__ row, const int* __restrict__ col,
                            int* __restrict__ fill, int2* __restrict__ srcs2,
                            const float* __restrict__ dinv, int E) {
  int e = blockIdx.x * blockDim.x + threadIdx.x;
  if (e < E) {
    int d = col[e];
    int r = row[e];
    int pos = atomicAdd(&fill[d], 1);
    srcs2[pos] = make_int2(r, __float_as_int(dinv[r]));
  }
}

// ----------------- gemm256 (R4): 64M x 128N tiles, counted-vmcnt dbuf, XCD swizzle ----

__global__ __launch_bounds__(256) void gemm256_kernel(
    const US* __restrict__ A, const US* __restrict__ Wt,
    US* __restrict__ C, int M) {
  __shared__ __align__(16) US shm[24576];      // 48KB
  int tid = threadIdx.x;
  int L = blockIdx.x;
  int xcd = L & 7, kk = L >> 3;
  int bmIdx = xcd * G256_TILES_PER_XCD + (kk >> 1);
  int bm = bmIdx * 64;
  int bn = (kk & 1) * 128;
  int lane = tid & 63;
  int w = tid >> 6;
  int wc = w * 32;
  int lm = lane & 15, lk = lane >> 4;
  int lr = lane >> 3, lc = lane & 7;
  int gc = lc ^ lr;

  floatx4 zero = {0.f, 0.f, 0.f, 0.f};
  floatx4 acc[4][2];
#pragma unroll
  for (int i = 0; i < 4; ++i)
#pragma unroll
    for (int j = 0; j < 2; ++j) acc[i][j] = zero;

  auto issue = [&](int k, int b) {
    int k0 = k * 64;
    US* As = shm + b * 4096;
    US* Bs = shm + 8192 + b * 8192;
#pragma unroll
    for (int i = 0; i < 2; ++i) {
      int rbase = i * 32 + w * 8;
      int r = min(bm + rbase + lr, M - 1);
      const US* ga = A + (size_t)r * GK + k0 + gc * 8;
      __builtin_amdgcn_global_load_lds((gptr_t)(const void*)ga,
                                       (lptr_t)(void*)&As[rbase * 64], 16, 0, 0);
    }
#pragma unroll
    for (int i = 0; i < 4; ++i) {
      int rbase = i * 32 + w * 8;
      int r = bn + rbase + lr;                 // Wt rows [bn, bn+128)
      const US* gb = Wt + (size_t)r * GK + k0 + gc * 8;
      __builtin_amdgcn_global_load_lds((gptr_t)(const void*)gb,
                                       (lptr_t)(void*)&Bs[rbase * 64], 16, 0, 0);
    }
  };

  issue(0, 0);
#pragma unroll
  for (int k = 0; k < 4; ++k) {
    if (k < 3) {
      issue(k + 1, (k + 1) & 1);
      asm volatile("s_waitcnt vmcnt(6)" ::: "memory");   // tile-k done, k+1 in flight
    } else {
      asm volatile("s_waitcnt vmcnt(0)" ::: "memory");
    }
    __builtin_amdgcn_sched_barrier(0);
    __builtin_amdgcn_s_barrier();
    const US* As = shm + (k & 1) * 4096;
    const US* Bs = shm + 8192 + (k & 1) * 8192;
#pragma unroll
    for (int s = 0; s < 2; ++s) {
      short8 af[4], bfr[2];
#pragma unroll
      for (int i = 0; i < 4; ++i) {
        int row = i * 16 + lm;
        int c = (s * 4 + lk) ^ (row & 7);
        af[i] = *(const short8*)&As[row * 64 + c * 8];
      }
#pragma unroll
      for (int j = 0; j < 2; ++j) {
        int row = wc + j * 16 + lm;
        int c = (s * 4 + lk) ^ (row & 7);
        bfr[j] = *(const short8*)&Bs[row * 64 + c * 8];
      }
#pragma unroll
      for (int i = 0; i < 4; ++i)
#pragma unroll
        for (int j = 0; j < 2; ++j)
          acc[i][j] = __builtin_amdgcn_mfma_f32_16x16x32_bf16(af[i], bfr[j], acc[i][j], 0, 0, 0);
    }
    __builtin_amdgcn_s_barrier();
  }

  // epilogue: LDS stage (64 rows x 128 cols, pad 8) -> coalesced 16B stores
  {
    constexpr int LDC = 136;
    US* Cs = shm;                              // 64*136 = 8704 US <= 24576
#pragma unroll
    for (int i = 0; i < 4; ++i)
#pragma unroll
      for (int j = 0; j < 2; ++j) {
        int colg = wc + j * 16 + lm;
#pragma unroll
        for (int r = 0; r < 4; ++r)
          Cs[(i * 16 + lk * 4 + r) * LDC + colg] = f2bf(acc[i][j][r]);
      }
    __syncthreads();
#pragma unroll
    for (int c = 0; c < 4; ++c) {              // 1024 = 64 rows x 16 chunks
      int idx = tid + c * 256;
      int row = idx >> 4;
      int ch = idx & 15;
      uint4 v = *(const uint4*)&Cs[row * LDC + ch * 8];
      if (bm + row < M) *(uint4*)&C[(size_t)(bm + row) * 256 + bn + ch * 8] = v;
    }
  }
}

// ----------------- gemm64 (R4) -----------------

__global__ __launch_bounds__(256) void gemm64_kernel(
    const US* __restrict__ A, const US* __restrict__ Wt,
    US* __restrict__ C, int M) {
  __shared__ __align__(16) US shm[24576];      // 48KB
  int tid = threadIdx.x;
  int L = blockIdx.x;
  int b = (L & 7) * G64_TILES_PER_XCD + (L >> 3);
  int bm = b * 128;
  int lane = tid & 63;
  int w = tid >> 6;
  int wr = w * 32;
  int lm = lane & 15, lk = lane >> 4;
  int lr = lane >> 3, lc = lane & 7;
  int gc = lc ^ lr;

  floatx4 zero = {0.f, 0.f, 0.f, 0.f};
  floatx4 acc[2][4];
#pragma unroll
  for (int i = 0; i < 2; ++i)
#pragma unroll
    for (int j = 0; j < 4; ++j) acc[i][j] = zero;

  auto issue = [&](int k, int bb) {
    int k0 = k * 64;
    US* As = shm + bb * 8192;
    US* Bs = shm + 16384 + bb * 4096;
#pragma unroll
    for (int i = 0; i < 4; ++i) {
      int rbase = i * 32 + w * 8;
      int r = min(bm + rbase + lr, M - 1);
      const US* ga = A + (size_t)r * GK + k0 + gc * 8;
      __builtin_amdgcn_global_load_lds((gptr_t)(const void*)ga,
                                       (lptr_t)(void*)&As[rbase * 64], 16, 0, 0);
    }
#pragma unroll
    for (int i = 0; i < 2; ++i) {
      int rbase = i * 32 + w * 8;
      int r = rbase + lr;
      const US* gb = Wt + (size_t)r * GK + k0 + gc * 8;
      __builtin_amdgcn_global_load_lds((gptr_t)(const void*)gb,
                                       (lptr_t)(void*)&Bs[rbase * 64], 16, 0, 0);
    }
  };

  issue(0, 0);
#pragma unroll
  for (int k = 0; k < 4; ++k) {
    if (k < 3) {
      issue(k + 1, (k + 1) & 1);
      asm volatile("s_waitcnt vmcnt(6)" ::: "memory");
    } else {
      asm volatile("s_waitcnt vmcnt(0)" ::: "memory");
    }
    __builtin_amdgcn_sched_barrier(0);
    __builtin_amdgcn_s_barrier();
    const US* As = shm + (k & 1) * 8192;
    const US* Bs = shm + 16384 + (k & 1) * 4096;
#pragma unroll
    for (int s = 0; s < 2; ++s) {
      short8 af[2], bfr[4];
#pragma unroll
      for (int i = 0; i < 2; ++i) {
        int row = wr + i * 16 + lm;
        int c = (s * 4 + lk) ^ (row & 7);
        af[i] = *(const short8*)&As[row * 64 + c * 8];
      }
#pragma unroll
      for (int j = 0; j < 4; ++j) {
        int row = j * 16 + lm;
        int c = (s * 4 + lk) ^ (row & 7);
        bfr[j] = *(const short8*)&Bs[row * 64 + c * 8];
      }
#pragma unroll
      for (int i = 0; i < 2; ++i)
#pragma unroll
        for (int j = 0; j < 4; ++j)
          acc[i][j] = __builtin_amdgcn_mfma_f32_16x16x32_bf16(af[i], bfr[j], acc[i][j], 0, 0, 0);
    }
    __builtin_amdgcn_s_barrier();
  }

  {
    constexpr int LDC = 72;
    US* Cs = shm;                              // 128*72 = 9216 US
#pragma unroll
    for (int i = 0; i < 2; ++i)
#pragma unroll
      for (int j = 0; j < 4; ++j) {
        int colg = j * 16 + lm;
#pragma unroll
        for (int r = 0; r < 4; ++r)
          Cs[(wr + i * 16 + lk * 4 + r) * LDC + colg] = f2bf(acc[i][j][r]);
      }
    __syncthreads();
#pragma unroll
    for (int c = 0; c < 4; ++c) {
      int idx = tid + c * 256;
      int row = idx >> 3;       // 0..127
      int ch = idx & 7;         // 0..7
      uint4 v = *(const uint4*)&Cs[row * LDC + ch * 8];
      if (bm + row < M) *(uint4*)&C[(size_t)(bm + row) * 64 + ch * 8] = v;
    }
  }
}

// ----------------- pull aggregation (R4 proven: ~58us, fabric-floored) -----------------
// The ~3.7 TB/s L2-miss-path rate at ~186MB is the structural floor for random
// pull-gather: established by R1 (2x in-flight: null), R3 (fusion: worse),
// R6/R7/R8 (three dim-slice locality schemes: FETCH invariant at ~200MB).

template <bool RELU>
__global__ __launch_bounds__(256) void agg256_kernel(
    const US* __restrict__ t, US* __restrict__ out,
    const int* __restrict__ row_ptr, const int* __restrict__ cnt,
    const int2* __restrict__ srcs2, const float* __restrict__ dinv,
    const float* __restrict__ bias) {
  int L = blockIdx.x;
  int jg = (L & 7) * AGG_BLKS_PER_XCD + (L >> 3);
  int j = jg * 4 + (threadIdx.x >> 6);
  if (j >= N_NODES) return;                    // wave-uniform, no barriers below
  int lane = threadIdx.x & 63;
  int h = lane & 31;
  int eidx = lane >> 5;
  int base = h * 8;
  int start = row_ptr[j];
  int n = cnt[j];
  float a[8];
#pragma unroll
  for (int k = 0; k < 8; ++k) a[k] = 0.f;

  int i = 0;
  for (; i + 7 < n; i += 8) {
    int2 e0 = srcs2[start + i + 0 + eidx];
    int2 e1 = srcs2[start + i + 2 + eidx];
    int2 e2 = srcs2[start + i + 4 + eidx];
    int2 e3 = srcs2[start + i + 6 + eidx];
    uint4 v0 = *(const uint4*)(t + (size_t)e0.x * 256 + base);
    uint4 v1 = *(const uint4*)(t + (size_t)e1.x * 256 + base);
    uint4 v2 = *(const uint4*)(t + (size_t)e2.x * 256 + base);
    uint4 v3 = *(const uint4*)(t + (size_t)e3.x * 256 + base);
    float w0 = __int_as_float(e0.y), w1 = __int_as_float(e1.y);
    float w2 = __int_as_float(e2.y), w3 = __int_as_float(e3.y);
    a[0] += bflo(v0.x) * w0; a[1] += bfhi(v0.x) * w0;
    a[2] += bflo(v0.y) * w0; a[3] += bfhi(v0.y) * w0;
    a[4] += bflo(v0.z) * w0; a[5] += bfhi(v0.z) * w0;
    a[6] += bflo(v0.w) * w0; a[7] += bfhi(v0.w) * w0;
    a[0] += bflo(v1.x) * w1; a[1] += bfhi(v1.x) * w1;
    a[2] += bflo(v1.y) * w1; a[3] += bfhi(v1.y) * w1;
    a[4] += bflo(v1.z) * w1; a[5] += bfhi(v1.z) * w1;
    a[6] += bflo(v1.w) * w1; a[7] += bfhi(v1.w) * w1;
    a[0] += bflo(v2.x) * w2; a[1] += bfhi(v2.x) * w2;
    a[2] += bflo(v2.y) * w2; a[3] += bfhi(v2.y) * w2;
    a[4] += bflo(v2.z) * w2; a[5] += bfhi(v2.z) * w2;
    a[6] += bflo(v2.w) * w2; a[7] += bfhi(v2.w) * w2;
    a[0] += bflo(v3.x) * w3; a[1] += bfhi(v3.x) * w3;
    a[2] += bflo(v3.y) * w3; a[3] += bfhi(v3.y) * w3;
    a[4] += bflo(v3.z) * w3; a[5] += bfhi(v3.z) * w3;
    a[6] += bflo(v3.w) * w3; a[7] += bfhi(v3.w) * w3;
  }
  for (; i < n; i += 2) {
    int idx = i + eidx;
    int cl = min(idx, n - 1);
    int2 e = srcs2[start + cl];
    float w = (idx < n) ? __int_as_float(e.y) : 0.f;
    uint4 v = *(const uint4*)(t + (size_t)e.x * 256 + base);
    a[0] += bflo(v.x) * w; a[1] += bfhi(v.x) * w;
    a[2] += bflo(v.y) * w; a[3] += bfhi(v.y) * w;
    a[4] += bflo(v.z) * w; a[5] += bfhi(v.z) * w;
    a[6] += bflo(v.w) * w; a[7] += bfhi(v.w) * w;
  }
#pragma unroll
  for (int k = 0; k < 8; ++k) a[k] += __shfl_xor(a[k], 32, 64);

  float dj = dinv[j];
  uint4 vj = *(const uint4*)(t + (size_t)j * 256 + base);
  float4 bv0 = *(const float4*)(bias + base);
  float4 bv1 = *(const float4*)(bias + base + 4);
  float r[8];
  r[0] = (a[0] + bflo(vj.x) * dj) * dj + bv0.x;
  r[1] = (a[1] + bfhi(vj.x) * dj) * dj + bv0.y;
  r[2] = (a[2] + bflo(vj.y) * dj) * dj + bv0.z;
  r[3] = (a[3] + bfhi(vj.y) * dj) * dj + bv0.w;
  r[4] = (a[4] + bflo(vj.z) * dj) * dj + bv1.x;
  r[5] = (a[5] + bfhi(vj.z) * dj) * dj + bv1.y;
  r[6] = (a[6] + bflo(vj.w) * dj) * dj + bv1.z;
  r[7] = (a[7] + bfhi(vj.w) * dj) * dj + bv1.w;
  if (RELU) {
#pragma unroll
    for (int k = 0; k < 8; ++k) r[k] = fmaxf(r[k], 0.f);
  }
  if (lane < 32) {
    US o[8];
#pragma unroll
    for (int k = 0; k < 8; ++k) o[k] = f2bf(r[k]);
    *(uint4*)(out + (size_t)j * 256 + base) = *(const uint4*)o;
  }
}

// ----------------- fused agg64 + final dense + sigmoid (R3, proven) -----------------

__global__ __launch_bounds__(256) void aggfinal_kernel(
    const US* __restrict__ t, float* __restrict__ out,
    const int* __restrict__ row_ptr, const int* __restrict__ cnt,
    const int2* __restrict__ srcs2, const float* __restrict__ dinv,
    const float* __restrict__ b3, const float* __restrict__ W4,
    const float* __restrict__ b4, int M) {
  __shared__ float W4s[4096];
  __shared__ float b4s[64];
  __shared__ float hbuf[4][64];
  int tid = threadIdx.x;
#pragma unroll
  for (int it = 0; it < 16; ++it) W4s[it * 256 + tid] = W4[it * 256 + tid];
  if (tid < 64) b4s[tid] = b4[tid];
  __syncthreads();

  int wv = tid >> 6, lane = tid & 63;
  int g = lane & 15, eidx = lane >> 4;
  int base = g * 4;
#pragma unroll 1
  for (int q = 0; q < 4; ++q) {
    int j = blockIdx.x * 16 + wv * 4 + q;
    if (j >= M) break;
    int start = row_ptr[j];
    int n = cnt[j];
    float a[4] = {0.f, 0.f, 0.f, 0.f};
    int i = 0;
    for (; i + 7 < n; i += 8) {
      int2 e0 = srcs2[start + i + eidx];
      int2 e1 = srcs2[start + i + 4 + eidx];
      uint2 v0 = *(const uint2*)(t + (size_t)e0.x * 64 + base);
      uint2 v1 = *(const uint2*)(t + (size_t)e1.x * 64 + base);
      float w0 = __int_as_float(e0.y), w1 = __int_as_float(e1.y);
      a[0] += bflo(v0.x) * w0; a[1] += bfhi(v0.x) * w0;
      a[2] += bflo(v0.y) * w0; a[3] += bfhi(v0.y) * w0;
      a[0] += bflo(v1.x) * w1; a[1] += bfhi(v1.x) * w1;
      a[2] += bflo(v1.y) * w1; a[3] += bfhi(v1.y) * w1;
    }
    for (; i < n; i += 4) {
      int idx = i + eidx;
      int cl = min(idx, n - 1);
      int2 e = srcs2[start + cl];
      float w0 = (idx < n) ? __int_as_float(e.y) : 0.f;
      uint2 v = *(const uint2*)(t + (size_t)e.x * 64 + base);
      a[0] += bflo(v.x) * w0; a[1] += bfhi(v.x) * w0;
      a[2] += bflo(v.y) * w0; a[3] += bfhi(v.y) * w0;
    }
#pragma unroll
    for (int k = 0; k < 4; ++k) {
      a[k] += __shfl_xor(a[k], 16, 64);
      a[k] += __shfl_xor(a[k], 32, 64);
    }
    float dj = dinv[j];
    uint2 vj = *(const uint2*)(t + (size_t)j * 64 + base);
    float4 bv = *(const float4*)(b3 + base);
    float h0 = (a[0] + bflo(vj.x) * dj) * dj + bv.x;
    float h1 = (a[1] + bfhi(vj.x) * dj) * dj + bv.y;
    float h2 = (a[2] + bflo(vj.y) * dj) * dj + bv.z;
    float h3 = (a[3] + bfhi(vj.y) * dj) * dj + bv.w;
    if (lane < 16) {
      float4 hv = make_float4(h0, h1, h2, h3);
      *(float4*)&hbuf[wv][base] = hv;
    }
    asm volatile("s_waitcnt lgkmcnt(0)" ::: "memory");
    float acc = b4s[lane];
#pragma unroll 8
    for (int k = 0; k < 64; ++k) acc += hbuf[wv][k] * W4s[k * 64 + lane];
    out[(size_t)j * 64 + lane] = 1.0f / (1.0f + expf(-acc));
  }
}

// ----------------- driver -----------------

extern "C" void kernel_launch(void* const* d_in, const int* in_sizes, int n_in,
                              void* d_out, int out_size, void* d_ws, size_t ws_size,
                              hipStream_t stream) {
  const float* x  = (const float*)d_in[0];
  const int* ei   = (const int*)d_in[1];
  const float* W1 = (const float*)d_in[2];
  const float* b1 = (const float*)d_in[3];
  const float* W2 = (const float*)d_in[4];
  const float* b2 = (const float*)d_in[5];
  const float* W3 = (const float*)d_in[6];
  const float* b3 = (const float*)d_in[7];
  const float* W4 = (const float*)d_in[8];
  const float* b4 = (const float*)d_in[9];
  float* outp = (float*)d_out;

  const int N = N_NODES, E = N_EDGES;
  const int* row = ei;
  const int* col = ei + E;

  US* Ab = (US*)d_ws;                         // [N,256] bf16 ping
  US* Bb = Ab + (size_t)N * 256;              // [N,256] bf16 pong
  US* B64 = Bb + (size_t)N * 256;             // [N,64] (G6)
  float* dinv = (float*)(B64 + (size_t)N * 64);
  int* cnt = (int*)(dinv + N);
  int* row_ptr = cnt + N;
  int* fill = row_ptr + N;
  int* bsums = fill + N;                      // [256]
  int2* srcs2 = (int2*)(bsums + 256);         // [E]
  US* Wt1 = (US*)(srcs2 + E);                 // [256,256]
  US* Wt2 = Wt1 + 256 * 256;                  // [256,256]
  US* Wt3 = Wt2 + 256 * 256;                  // [64,256]

  hipMemsetAsync(cnt, 0, N * sizeof(int), stream);
  pre0_kernel<<<1024, 256, 0, stream>>>(col, cnt, x, Ab, W1, W2, W3,
                                        Wt1, Wt2, Wt3);
  int nblk = (N + 255) / 256;
  scan_block_kernel<<<nblk, 256, 0, stream>>>(cnt, row_ptr, bsums, dinv, N);
  scan_top_kernel<<<1, 256, 0, stream>>>(bsums, nblk);
  scan_add_kernel<<<nblk, 256, 0, stream>>>(row_ptr, fill, bsums, N);
  fill_kernel<<<(E + 255) / 256, 256, 0, stream>>>(row, col, fill, srcs2, dinv, E);

  const int g256 = 8 * G256_TILES_PER_XCD * 2;   // 1568
  const int gagg = 8 * AGG_BLKS_PER_XCD;         // 12544
  const int g64g = 8 * G64_TILES_PER_XCD;        // 392

  gemm256_kernel<<<g256, 256, 0, stream>>>(Ab, Wt1, Bb, N);
  agg256_kernel<true><<<gagg, 256, 0, stream>>>(Bb, Ab, row_ptr, cnt, srcs2, dinv, b1);
  for (int l = 0; l < 4; ++l) {
    gemm256_kernel<<<g256, 256, 0, stream>>>(Ab, Wt2, Bb, N);
    agg256_kernel<true><<<gagg, 256, 0, stream>>>(Bb, Ab, row_ptr, cnt, srcs2, dinv, b2);
  }
  gemm64_kernel<<<g64g, 256, 0, stream>>>(Ab, Wt3, B64, N);
  aggfinal_kernel<<<(N + 15) / 16, 256, 0, stream>>>(B64, outp, row_ptr, cnt, srcs2, dinv,
                                                     b3, W4, b4, N);
}